// Round 11
// baseline (273.332 us; speedup 1.0000x reference)
//
#include <hip/hip_runtime.h>
#include <math.h>

// Problem constants
#define HH 2048
#define EE 64
#define TOPK 8
#define NT 16384
#define MT 32            // tokens per WG
#define KC 128           // K elems per chunk (tile: 32 tokens x 128 k fp32)
#define NCH 16           // HH / KC
#define LS 68            // slog row stride (floats)

typedef __attribute__((ext_vector_type(8)))  short short8;  // 8 bf16 (4 VGPRs)
typedef __attribute__((ext_vector_type(16))) float f32x16;  // 32x32 MFMA acc

#define GLB(p) ((const __attribute__((address_space(1))) void*)(p))
#define LDS(p) ((__attribute__((address_space(3))) void*)(p))

// 3-limb bf16 split (rounds-3..9 harness-passing version)
static __device__ __forceinline__ void cvt3(const float4& a, const float4& b,
                                            short8& h, short8& m, short8& l)
{
    const float v[8] = {a.x, a.y, a.z, a.w, b.x, b.y, b.z, b.w};
#pragma unroll
    for (int i = 0; i < 8; ++i) {
        const unsigned int u = __float_as_uint(v[i]);
        h[i] = (short)(u >> 16);
        const float r1 = v[i] - __uint_as_float(u & 0xffff0000u);
        const unsigned int u1 = __float_as_uint(r1);
        m[i] = (short)(u1 >> 16);
        const float r2 = r1 - __uint_as_float(u1 & 0xffff0000u);
        const unsigned int u2 = __float_as_uint(r2);
        l[i] = (short)((u2 + 0x7fffu + ((u2 >> 16) & 1u)) >> 16);
    }
}

// ---------------- Pre-kernel: W -> fragment-ready 3-limb bf16 ----------------
// (rounds-5/7/8/9 harness-passing version)
__global__ __launch_bounds__(256) void wsplit(
    const float* __restrict__ w, short* __restrict__ wsw)
{
    const int e = blockIdx.x;
    const int o = threadIdx.x;
    const int k = o * 8;
    const float4 a = *(const float4*)(w + (size_t)e * HH + k);
    const float4 b = *(const float4*)(w + (size_t)e * HH + k + 4);
    short8 h, m, l;
    cvt3(a, b, h, m, l);

    const int eb  = e >> 5, lr = e & 31;
    const int s16 = o >> 1;
    const int l5  = o & 1;
    const int lane = l5 * 32 + lr;
    short* dst = wsw + (((size_t)(eb * 128 + s16) * 3) * 64 + lane) * 8;
    *(short8*)(dst)           = h;
    *(short8*)(dst + 64 * 8)  = m;
    *(short8*)(dst + 128 * 8) = l;
}

// ---------------- PROBE 1: x-staging path only ----------------
// R9's loop with compute removed: global_load_lds DMA + barrier chain.
__global__ __launch_bounds__(512, 4) void probe_stage(
    const float* __restrict__ x, float* __restrict__ scr)
{
    __shared__ __align__(16) float xtile[2][MT * KC];
    const int t    = threadIdx.x;
    const int tok0 = blockIdx.x * MT;
    const int r0   = t >> 5;
    const int u0s  = t & 31;
    const int wbase = (t & ~63) * 4;

    auto stage = [&](int c, int buf) {
#pragma unroll
        for (int j = 0; j < 2; ++j) {
            const int r = r0 + j * 16;
            const size_t goff = (size_t)(tok0 + r) * HH + c * KC
                              + ((u0s ^ (r & 7)) << 2);
            float* lp = &xtile[buf][wbase + j * 2048];
            __builtin_amdgcn_global_load_lds(GLB(x + goff), LDS(lp), 16, 0, 0);
        }
    };

    stage(0, 0);
    __syncthreads();
#pragma unroll 1
    for (int c = 0; c < NCH; ++c) {
        if (c + 1 < NCH) stage(c + 1, (c + 1) & 1);
        __syncthreads();
    }
    if (t == 0) scr[blockIdx.x] = xtile[0][0] + xtile[1][1];   // keep live
}

// ---------------- PROBE 2: W-load + cvt3 + MFMA path only ----------------
// R9's loop with staging removed. LDS zero-initialized once (no denormal /
// uninitialized reads skewing timing).
__global__ __launch_bounds__(512, 4) void probe_compute(
    const short* __restrict__ wsw, float* __restrict__ scr)
{
    __shared__ __align__(16) float xtile[2][MT * KC];
    const int t    = threadIdx.x;
    const int wv   = t >> 6;
    const int lane = t & 63;
    const int eb   = wv & 1;
    const int kq   = wv >> 1;
    const int l5   = lane >> 5;
    const int lr   = lane & 31;

    // one-time zero init (16 floats/thread, outside the timed-loop pattern)
#pragma unroll
    for (int i = 0; i < 8; ++i) {
        xtile[0][t * 8 + i] = 0.f;
        xtile[1][t * 8 + i] = 0.f;
    }

    f32x16 accM = {0}, accS = {0};
    __syncthreads();
#pragma unroll 1
    for (int c = 0; c < NCH; ++c) {
        const int buf = c & 1;
#pragma unroll
        for (int st = 0; st < 2; ++st) {
            const int s    = kq * 2 + st;
            const int s16g = c * 8 + s;
            const short8* wp = (const short8*)wsw
                             + ((size_t)(eb * 128 + s16g) * 3) * 64 + lane;
            const short8 B0 = wp[0];
            const short8 B1 = wp[64];
            const short8 B2 = wp[128];
            const int v0 = s * 4 + l5 * 2;
            const float4 f0 = *(const float4*)
                &xtile[buf][lr * KC + ((v0      ^ (lr & 7)) << 2)];
            const float4 f1 = *(const float4*)
                &xtile[buf][lr * KC + (((v0 + 1) ^ (lr & 7)) << 2)];
            short8 Ah, Am, Al;
            cvt3(f0, f1, Ah, Am, Al);
            accM = __builtin_amdgcn_mfma_f32_32x32x16_bf16(Ah, B0, accM, 0, 0, 0);
            accS = __builtin_amdgcn_mfma_f32_32x32x16_bf16(Ah, B1, accS, 0, 0, 0);
            accS = __builtin_amdgcn_mfma_f32_32x32x16_bf16(Am, B0, accS, 0, 0, 0);
            accS = __builtin_amdgcn_mfma_f32_32x32x16_bf16(Ah, B2, accS, 0, 0, 0);
            accS = __builtin_amdgcn_mfma_f32_32x32x16_bf16(Al, B0, accS, 0, 0, 0);
            accS = __builtin_amdgcn_mfma_f32_32x32x16_bf16(Am, B1, accS, 0, 0, 0);
        }
        __syncthreads();
    }
    if (t == 0) scr[512 + blockIdx.x] = accM[0] + accS[0];     // keep live
}

// ---------------- Main kernel (byte-identical to round 9) ----------------
__global__ __launch_bounds__(512, 4) void router_fused(
    const float* __restrict__ x,
    const short* __restrict__ wsw,
    float* __restrict__ out_logits,
    float* __restrict__ out_wts,
    float* __restrict__ out_idx)
{
    __shared__ __align__(16) float xtile[2][MT * KC];
    float* slog = (float*)xtile;

    const int t    = threadIdx.x;
    const int wv   = t >> 6;
    const int lane = t & 63;
    const int eb   = wv & 1;
    const int kq   = wv >> 1;
    const int l5   = lane >> 5;
    const int lr   = lane & 31;
    const int tok0 = blockIdx.x * MT;

    const int r0 = t >> 5;
    const int u0s = t & 31;
    const int wbase = (t & ~63) * 4;

    f32x16 accM = {0}, accS = {0};

    auto stage = [&](int c, int buf) {
#pragma unroll
        for (int j = 0; j < 2; ++j) {
            const int r = r0 + j * 16;
            const size_t goff = (size_t)(tok0 + r) * HH + c * KC
                              + ((u0s ^ (r & 7)) << 2);
            float* lp = &xtile[buf][wbase + j * 2048];
            __builtin_amdgcn_global_load_lds(GLB(x + goff), LDS(lp), 16, 0, 0);
        }
    };

    auto chunk = [&](int c, int buf) {
#pragma unroll
        for (int st = 0; st < 2; ++st) {
            const int s    = kq * 2 + st;
            const int s16g = c * 8 + s;
            const short8* wp = (const short8*)wsw
                             + ((size_t)(eb * 128 + s16g) * 3) * 64 + lane;
            const short8 B0 = wp[0];
            const short8 B1 = wp[64];
            const short8 B2 = wp[128];
            const int v0 = s * 4 + l5 * 2;
            const float4 f0 = *(const float4*)
                &xtile[buf][lr * KC + ((v0      ^ (lr & 7)) << 2)];
            const float4 f1 = *(const float4*)
                &xtile[buf][lr * KC + (((v0 + 1) ^ (lr & 7)) << 2)];
            short8 Ah, Am, Al;
            cvt3(f0, f1, Ah, Am, Al);
            accM = __builtin_amdgcn_mfma_f32_32x32x16_bf16(Ah, B0, accM, 0, 0, 0);
            accS = __builtin_amdgcn_mfma_f32_32x32x16_bf16(Ah, B1, accS, 0, 0, 0);
            accS = __builtin_amdgcn_mfma_f32_32x32x16_bf16(Am, B0, accS, 0, 0, 0);
            accS = __builtin_amdgcn_mfma_f32_32x32x16_bf16(Ah, B2, accS, 0, 0, 0);
            accS = __builtin_amdgcn_mfma_f32_32x32x16_bf16(Al, B0, accS, 0, 0, 0);
            accS = __builtin_amdgcn_mfma_f32_32x32x16_bf16(Am, B1, accS, 0, 0, 0);
        }
    };

    stage(0, 0);
    __syncthreads();

#pragma unroll 1
    for (int c = 0; c < NCH; ++c) {
        if (c + 1 < NCH) stage(c + 1, (c + 1) & 1);
        chunk(c, c & 1);
        __syncthreads();
    }

    const int col = eb * 32 + lr;
#pragma unroll 1
    for (int q = 0; q < 4; ++q) {
        if (kq == q) {
#pragma unroll
            for (int r = 0; r < 16; ++r) {
                const int row = (r & 3) + 8 * (r >> 2) + 4 * l5;
                const float val = accM[r] + accS[r];
                if (q == 0) slog[row * LS + col] = val;
                else        slog[row * LS + col] += val;
            }
        }
        __syncthreads();
    }

    {
        const int row = t >> 4;
        const int c4  = (t & 15) * 4;
        const float4 o0 = *(const float4*)&slog[row * LS + c4];
        *(float4*)(out_logits + (size_t)(tok0 + row) * EE + c4) = o0;
    }

    if (t < MT) {
        float tv[TOPK];
        int   ti[TOPK];
#pragma unroll
        for (int q = 0; q < TOPK; ++q) { tv[q] = -INFINITY; ti[q] = 0; }

        for (int e = 0; e < EE; ++e) {
            const float val = slog[t * LS + e];
            if (val > tv[TOPK - 1]) {
                tv[TOPK - 1] = val;
                ti[TOPK - 1] = e;
#pragma unroll
                for (int q = TOPK - 1; q > 0; --q) {
                    if (tv[q] > tv[q - 1]) {
                        float fv = tv[q]; tv[q] = tv[q - 1]; tv[q - 1] = fv;
                        int   fi = ti[q]; ti[q] = ti[q - 1]; ti[q - 1] = fi;
                    }
                }
            }
        }

        const float m = tv[0];
        float ew[TOPK];
        float sum = 0.f;
#pragma unroll
        for (int q = 0; q < TOPK; ++q) { ew[q] = expf(tv[q] - m); sum += ew[q]; }
        const float inv = 1.f / sum;

        const size_t tok = (size_t)(tok0 + t);
        float4 w0, w1, i0, i1;
        w0.x = ew[0] * inv; w0.y = ew[1] * inv; w0.z = ew[2] * inv; w0.w = ew[3] * inv;
        w1.x = ew[4] * inv; w1.y = ew[5] * inv; w1.z = ew[6] * inv; w1.w = ew[7] * inv;
        i0.x = (float)ti[0]; i0.y = (float)ti[1]; i0.z = (float)ti[2]; i0.w = (float)ti[3];
        i1.x = (float)ti[4]; i1.y = (float)ti[5]; i1.z = (float)ti[6]; i1.w = (float)ti[7];
        *(float4*)(out_wts + tok * TOPK)     = w0;
        *(float4*)(out_wts + tok * TOPK + 4) = w1;
        *(float4*)(out_idx + tok * TOPK)     = i0;
        *(float4*)(out_idx + tok * TOPK + 4) = i1;
    }
}

extern "C" void kernel_launch(void* const* d_in, const int* in_sizes, int n_in,
                              void* d_out, int out_size, void* d_ws, size_t ws_size,
                              hipStream_t stream) {
    const float* x = (const float*)d_in[0];   // hidden_states [4,4096,2048] fp32
    const float* w = (const float*)d_in[1];   // gate_w [64,2048] fp32
    float* out        = (float*)d_out;
    float* out_logits = out;                               // 16384*64
    float* out_wts    = out + (size_t)NT * EE;             // 16384*8
    float* out_idx    = out_wts + (size_t)NT * TOPK;       // 16384*8
    short* wsw = (short*)d_ws;                             // 768 KB limb planes
    float* scr = (float*)((char*)d_ws + (1 << 20));        // probe scratch

    hipLaunchKernelGGL(wsplit, dim3(EE), dim3(256), 0, stream, w, wsw);
    // Ablation probes (write to workspace only; diagnostic round)
    hipLaunchKernelGGL(probe_stage,   dim3(NT / MT), dim3(512), 0, stream, x, scr);
    hipLaunchKernelGGL(probe_compute, dim3(NT / MT), dim3(512), 0, stream, wsw, scr);
    // Real kernel (byte-identical to round 9)
    hipLaunchKernelGGL(router_fused, dim3(NT / MT), dim3(512), 0, stream,
                       x, wsw, out_logits, out_wts, out_idx);
}